// Round 4
// baseline (253.847 us; speedup 1.0000x reference)
//
#include <hip/hip_runtime.h>

// y[rows[k]] += vals[k] * x[cols[k]] — M=N=262144, NNZ=8388608, out 512x512 f32.
// Pipeline: init cursors -> block-local counting sort (per-wave hist/cursors) +
// coalesced scatter into 64 row-bins -> per-(bin,slice) LDS accumulation ->
// slice reduction. No global atomics on y; only 64-bin reservation atomics.

#define BINS         64
#define ROW_SHIFT    12          // 4096 rows per bin
#define ROWS_PER_BIN 4096
#define ENT          2048        // entries per scatter block
#define IPT          8           // items per thread (256 threads)
#define SLICES       16

// ---------------- fallback path (R1, known-correct) ----------------

__global__ __launch_bounds__(256) void zero_out_kernel(float* __restrict__ y, int n) {
    int i = blockIdx.x * blockDim.x + threadIdx.x;
    if (i < n) y[i] = 0.0f;
}

__global__ __launch_bounds__(256) void spmv_coo_scatter(
    const float* __restrict__ vals, const int* __restrict__ rows,
    const int* __restrict__ cols, const float* __restrict__ x,
    float* __restrict__ y, int nnz)
{
    int i = (blockIdx.x * blockDim.x + threadIdx.x) * 4;
    if (i + 3 < nnz) {
        float4 v = *reinterpret_cast<const float4*>(vals + i);
        int4   r = *reinterpret_cast<const int4*>(rows + i);
        int4   c = *reinterpret_cast<const int4*>(cols + i);
        atomicAdd(&y[r.x], v.x * x[c.x]);
        atomicAdd(&y[r.y], v.y * x[c.y]);
        atomicAdd(&y[r.z], v.z * x[c.z]);
        atomicAdd(&y[r.w], v.w * x[c.w]);
    } else {
        for (; i < nnz; ++i) atomicAdd(&y[rows[i]], vals[i] * x[cols[i]]);
    }
}

// ---------------- binned path ----------------

__global__ __launch_bounds__(64) void init_cursors(unsigned* __restrict__ gcur) {
    gcur[threadIdx.x] = 0u;
}

// Block-local counting sort with per-wave histograms & cursors, coalesced copy-out.
__global__ __launch_bounds__(256, 8) void scatter3_kernel(
    const int*   __restrict__ rows, const int* __restrict__ cols,
    const float* __restrict__ vals, const float* __restrict__ x, int nnz,
    unsigned* __restrict__ gcur, unsigned cap,
    unsigned short* __restrict__ okeys, float* __restrict__ ocontrib)
{
    __shared__ unsigned cnt[4 * BINS];     // per-wave histograms
    __shared__ unsigned cur2[4 * BINS];    // per-wave placement cursors
    __shared__ unsigned lstart[BINS];      // block-level exclusive bin starts
    __shared__ unsigned totbin[BINS];
    __shared__ unsigned sresv[BINS];
    __shared__ int      dstb[BINS];        // global_base - local_start per bin
    __shared__ unsigned total_s;
    __shared__ unsigned short skey[ENT];
    __shared__ float          sval[ENT];
    __shared__ unsigned char  sbin[ENT];

    const int t   = threadIdx.x;
    const int wid = t >> 6;
    for (int i = t; i < 4 * BINS; i += 256) cnt[i] = 0u;
    __syncthreads();

    const int seg = blockIdx.x * ENT;

    int   rr[IPT];
    float ff[IPT];

    // Pass A: load triplets, fold x-gather into contrib, per-wave histogram.
    #pragma unroll
    for (int ch = 0; ch < IPT / 4; ++ch) {
        int base = seg + ch * 1024 + t * 4;
        if (base + 3 < nnz) {
            int4   r4 = *reinterpret_cast<const int4*>(rows + base);
            int4   c4 = *reinterpret_cast<const int4*>(cols + base);
            float4 v4 = *reinterpret_cast<const float4*>(vals + base);
            rr[ch*4+0] = r4.x; ff[ch*4+0] = v4.x * x[c4.x];
            rr[ch*4+1] = r4.y; ff[ch*4+1] = v4.y * x[c4.y];
            rr[ch*4+2] = r4.z; ff[ch*4+2] = v4.z * x[c4.z];
            rr[ch*4+3] = r4.w; ff[ch*4+3] = v4.w * x[c4.w];
        } else {
            #pragma unroll
            for (int j = 0; j < 4; ++j) {
                int idx = base + j;
                if (idx < nnz) { rr[ch*4+j] = rows[idx]; ff[ch*4+j] = vals[idx] * x[cols[idx]]; }
                else           { rr[ch*4+j] = -1; ff[ch*4+j] = 0.0f; }
            }
        }
    }
    #pragma unroll
    for (int j = 0; j < IPT; ++j)
        if (rr[j] >= 0) atomicAdd(&cnt[wid * BINS + (rr[j] >> ROW_SHIFT)], 1u);
    __syncthreads();

    // Per-bin totals + one global reservation per bin.
    if (t < BINS) {
        unsigned tot = cnt[t] + cnt[BINS + t] + cnt[2 * BINS + t] + cnt[3 * BINS + t];
        totbin[t] = tot;
        sresv[t]  = atomicAdd(&gcur[t], tot);
    }
    __syncthreads();
    if (t == 0) {
        unsigned run = 0;
        for (int b = 0; b < BINS; ++b) { lstart[b] = run; run += totbin[b]; }
        total_s = run;
    }
    __syncthreads();
    if (t < BINS) {
        dstb[t] = (int)sresv[t] - (int)lstart[t];
        unsigned o = lstart[t];
        cur2[t] = o;            o += cnt[t];
        cur2[BINS + t] = o;     o += cnt[BINS + t];
        cur2[2 * BINS + t] = o; o += cnt[2 * BINS + t];
        cur2[3 * BINS + t] = o;
    }
    __syncthreads();

    // Pass B: place entries grouped by bin in LDS (per-wave cursors, low contention).
    #pragma unroll
    for (int j = 0; j < IPT; ++j) {
        if (rr[j] >= 0) {
            int b = rr[j] >> ROW_SHIFT;
            unsigned p = atomicAdd(&cur2[wid * BINS + b], 1u);
            skey[p] = (unsigned short)(rr[j] & (ROWS_PER_BIN - 1));
            sval[p] = ff[j];
            sbin[p] = (unsigned char)b;
        }
    }
    __syncthreads();

    // Copy-out: LDS-contiguous == globally contiguous within each bin region.
    const unsigned total = total_s;
    for (unsigned i = t; i < total; i += 256) {
        int b = sbin[i];
        unsigned off = (unsigned)(dstb[b] + (int)i);
        if (off < cap) {
            size_t dst = (size_t)b * cap + off;
            okeys[dst]    = skey[i];
            ocontrib[dst] = sval[i];
        }
    }
}

// One block per (bin, slice): accumulate into 16 KB LDS acc, dump partials.
__global__ __launch_bounds__(256) void accum3_kernel(
    const unsigned short* __restrict__ okeys, const float* __restrict__ ocontrib,
    const unsigned* __restrict__ gcur, unsigned cap,
    float* __restrict__ partials)
{
    __shared__ float acc[ROWS_PER_BIN];
    const int t   = threadIdx.x;
    const int bin = blockIdx.x / SLICES;
    const int sl  = blockIdx.x % SLICES;

    #pragma unroll
    for (int i = 0; i < ROWS_PER_BIN / 1024; ++i) {
        int l = i * 1024 + t * 4;
        *reinterpret_cast<float4*>(&acc[l]) = make_float4(0.f, 0.f, 0.f, 0.f);
    }
    __syncthreads();

    unsigned count = gcur[bin];
    if (count > cap) count = cap;
    unsigned chunk = (count + SLICES - 1) / SLICES;
    chunk = (chunk + 3u) & ~3u;
    unsigned lo = (unsigned)sl * chunk;
    unsigned hi = lo + chunk; if (hi > count) hi = count;

    const unsigned short* k = okeys    + (size_t)bin * cap;
    const float*          c = ocontrib + (size_t)bin * cap;

    unsigned i = lo + (unsigned)t * 4u;
    for (; i + 3u < hi; i += 1024u) {
        ushort4 k4 = *reinterpret_cast<const ushort4*>(k + i);
        float4  c4 = *reinterpret_cast<const float4*>(c + i);
        atomicAdd(&acc[k4.x], c4.x);
        atomicAdd(&acc[k4.y], c4.y);
        atomicAdd(&acc[k4.z], c4.z);
        atomicAdd(&acc[k4.w], c4.w);
    }
    for (; i < hi; ++i) atomicAdd(&acc[k[i]], c[i]);
    __syncthreads();

    float* p = partials + (size_t)blockIdx.x * ROWS_PER_BIN;
    #pragma unroll
    for (int j = 0; j < ROWS_PER_BIN / 1024; ++j) {
        int l = j * 1024 + t * 4;
        *reinterpret_cast<float4*>(p + l) = *reinterpret_cast<const float4*>(&acc[l]);
    }
}

// Sum the SLICES partials per row (4 rows per thread, float4).
__global__ __launch_bounds__(256) void reduce3_kernel(
    const float* __restrict__ partials, float* __restrict__ y, int out_size)
{
    int r = (blockIdx.x * 256 + threadIdx.x) * 4;
    if (r + 3 >= out_size) {
        for (int q = r; q < out_size; ++q) {
            int bin = q >> ROW_SHIFT, local = q & (ROWS_PER_BIN - 1);
            const float* p = partials + ((size_t)bin * SLICES) * ROWS_PER_BIN + local;
            float s = 0.f;
            for (int j = 0; j < SLICES; ++j) s += p[(size_t)j * ROWS_PER_BIN];
            y[q] = s;
        }
        return;
    }
    int bin = r >> ROW_SHIFT, local = r & (ROWS_PER_BIN - 1);
    const float* p = partials + ((size_t)bin * SLICES) * ROWS_PER_BIN + local;
    float4 s = make_float4(0.f, 0.f, 0.f, 0.f);
    #pragma unroll
    for (int j = 0; j < SLICES; ++j) {
        float4 v = *reinterpret_cast<const float4*>(p + (size_t)j * ROWS_PER_BIN);
        s.x += v.x; s.y += v.y; s.z += v.z; s.w += v.w;
    }
    *reinterpret_cast<float4*>(y + r) = s;
}

extern "C" void kernel_launch(void* const* d_in, const int* in_sizes, int n_in,
                              void* d_out, int out_size, void* d_ws, size_t ws_size,
                              hipStream_t stream) {
    const float* x    = (const float*)d_in[0];
    const float* vals = (const float*)d_in[1];
    const int*   rows = (const int*)d_in[2];
    const int*   cols = (const int*)d_in[3];
    float* y = (float*)d_out;

    const int nnz = in_sizes[1];
    const int nb  = (nnz + ENT - 1) / ENT;                     // 4096
    unsigned cap = (unsigned)(nnz / BINS) + 8192u;             // ~22 sigma slack
    cap = (cap + 3u) & ~3u;

    auto align256 = [](size_t v) { return (v + 255) & ~(size_t)255; };
    size_t off_contrib  = 0;
    size_t off_keys     = align256(off_contrib + (size_t)BINS * cap * 4);
    size_t off_partials = align256(off_keys + (size_t)BINS * cap * 2);
    size_t off_gcur     = align256(off_partials + (size_t)BINS * SLICES * ROWS_PER_BIN * 4);
    size_t need         = align256(off_gcur + (size_t)BINS * 4);

    const bool ok = (out_size <= BINS * ROWS_PER_BIN) && (out_size % 4 == 0) &&
                    (need <= ws_size) && (nnz > 0);

    if (!ok) {
        zero_out_kernel<<<(out_size + 255) / 256, 256, 0, stream>>>(y, out_size);
        spmv_coo_scatter<<<(nnz + 1023) / 1024, 256, 0, stream>>>(vals, rows, cols, x, y, nnz);
        return;
    }

    char* w = (char*)d_ws;
    float*          ocontrib = (float*)(w + off_contrib);
    unsigned short* okeys    = (unsigned short*)(w + off_keys);
    float*          partials = (float*)(w + off_partials);
    unsigned*       gcur     = (unsigned*)(w + off_gcur);

    init_cursors<<<1, BINS, 0, stream>>>(gcur);
    scatter3_kernel<<<nb, 256, 0, stream>>>(rows, cols, vals, x, nnz, gcur, cap,
                                            okeys, ocontrib);
    accum3_kernel<<<BINS * SLICES, 256, 0, stream>>>(okeys, ocontrib, gcur, cap, partials);
    reduce3_kernel<<<(out_size / 4 + 255) / 256, 256, 0, stream>>>(partials, y, out_size);
}

// Round 5
// 235.930 us; speedup vs baseline: 1.0759x; 1.0759x over previous
//
#include <hip/hip_runtime.h>

// y[rows[k]] += vals[k] * x[cols[k]] — M=N=262144, NNZ=8388608, out 512x512 f32.
// Pipeline: init cursors -> block-local counting sort (wave-scan, per-wave
// hist/cursors) + coalesced scatter into 64 row-bins -> per-(bin,slice) LDS
// accumulation (1024-thr blocks, full wave occupancy) -> slice reduction.

#define BINS            64
#define ROW_SHIFT       12        // 4096 rows per bin
#define ROWS_PER_BIN    4096
#define ENT             4096      // entries per scatter block
#define SCATTER_THREADS 512
#define NWAVES          8         // SCATTER_THREADS / 64
#define IPT             8         // ENT / SCATTER_THREADS
#define SLICES          8
#define ACCUM_THREADS   1024

// ---------------- fallback path (R1, known-correct) ----------------

__global__ __launch_bounds__(256) void zero_out_kernel(float* __restrict__ y, int n) {
    int i = blockIdx.x * blockDim.x + threadIdx.x;
    if (i < n) y[i] = 0.0f;
}

__global__ __launch_bounds__(256) void spmv_coo_scatter(
    const float* __restrict__ vals, const int* __restrict__ rows,
    const int* __restrict__ cols, const float* __restrict__ x,
    float* __restrict__ y, int nnz)
{
    int i = (blockIdx.x * blockDim.x + threadIdx.x) * 4;
    if (i + 3 < nnz) {
        float4 v = *reinterpret_cast<const float4*>(vals + i);
        int4   r = *reinterpret_cast<const int4*>(rows + i);
        int4   c = *reinterpret_cast<const int4*>(cols + i);
        atomicAdd(&y[r.x], v.x * x[c.x]);
        atomicAdd(&y[r.y], v.y * x[c.y]);
        atomicAdd(&y[r.z], v.z * x[c.z]);
        atomicAdd(&y[r.w], v.w * x[c.w]);
    } else {
        for (; i < nnz; ++i) atomicAdd(&y[rows[i]], vals[i] * x[cols[i]]);
    }
}

// ---------------- binned path ----------------

__global__ __launch_bounds__(64) void init_cursors(unsigned* __restrict__ gcur) {
    gcur[threadIdx.x] = 0u;
}

// Block-local counting sort; wave-0 prefix scan; coalesced copy-out.
__global__ __launch_bounds__(SCATTER_THREADS, 8) void scatter4_kernel(
    const int*   __restrict__ rows, const int* __restrict__ cols,
    const float* __restrict__ vals, const float* __restrict__ x, int nnz,
    unsigned* __restrict__ gcur, unsigned cap,
    unsigned short* __restrict__ okeys, float* __restrict__ ocontrib)
{
    __shared__ unsigned cnt[NWAVES * BINS];   // per-wave histograms
    __shared__ unsigned cur2[NWAVES * BINS];  // per-wave placement cursors
    __shared__ int      dstb[BINS];           // global_base - local_start
    __shared__ unsigned total_s;
    __shared__ unsigned short skey[ENT];
    __shared__ float          sval[ENT];
    __shared__ unsigned char  sbin[ENT];

    const int t   = threadIdx.x;
    const int wid = t >> 6;
    for (int i = t; i < NWAVES * BINS; i += SCATTER_THREADS) cnt[i] = 0u;
    __syncthreads();

    const int seg = blockIdx.x * ENT;
    int   rr[IPT];
    float ff[IPT];

    // Pass A: vector-load triplets, fold x-gather, per-wave histogram.
    #pragma unroll
    for (int ch = 0; ch < IPT / 4; ++ch) {
        int base = seg + ch * (SCATTER_THREADS * 4) + t * 4;
        if (base + 3 < nnz) {
            int4   r4 = *reinterpret_cast<const int4*>(rows + base);
            int4   c4 = *reinterpret_cast<const int4*>(cols + base);
            float4 v4 = *reinterpret_cast<const float4*>(vals + base);
            rr[ch*4+0] = r4.x; ff[ch*4+0] = v4.x * x[c4.x];
            rr[ch*4+1] = r4.y; ff[ch*4+1] = v4.y * x[c4.y];
            rr[ch*4+2] = r4.z; ff[ch*4+2] = v4.z * x[c4.z];
            rr[ch*4+3] = r4.w; ff[ch*4+3] = v4.w * x[c4.w];
        } else {
            #pragma unroll
            for (int j = 0; j < 4; ++j) {
                int idx = base + j;
                if (idx < nnz) { rr[ch*4+j] = rows[idx]; ff[ch*4+j] = vals[idx] * x[cols[idx]]; }
                else           { rr[ch*4+j] = -1; ff[ch*4+j] = 0.0f; }
            }
        }
    }
    #pragma unroll
    for (int j = 0; j < IPT; ++j)
        if (rr[j] >= 0) atomicAdd(&cnt[wid * BINS + (rr[j] >> ROW_SHIFT)], 1u);
    __syncthreads();

    // Wave 0 (lanes 0..63 == bins): totals, reservation, prefix scan, cursors.
    if (t < BINS) {
        unsigned tot = 0;
        #pragma unroll
        for (int w = 0; w < NWAVES; ++w) tot += cnt[w * BINS + t];
        unsigned resv = atomicAdd(&gcur[t], tot);
        // inclusive wave-wide scan over 64 lanes
        unsigned inc = tot;
        #pragma unroll
        for (int off = 1; off < 64; off <<= 1) {
            unsigned v = __shfl_up(inc, off, 64);
            if (t >= off) inc += v;
        }
        unsigned lst = inc - tot;             // exclusive start
        dstb[t] = (int)resv - (int)lst;
        if (t == 63) total_s = inc;
        unsigned o = lst;
        #pragma unroll
        for (int w = 0; w < NWAVES; ++w) { cur2[w * BINS + t] = o; o += cnt[w * BINS + t]; }
    }
    __syncthreads();

    // Pass B: place entries bin-grouped in LDS via per-wave cursors.
    #pragma unroll
    for (int j = 0; j < IPT; ++j) {
        if (rr[j] >= 0) {
            int b = rr[j] >> ROW_SHIFT;
            unsigned p = atomicAdd(&cur2[wid * BINS + b], 1u);
            skey[p] = (unsigned short)(rr[j] & (ROWS_PER_BIN - 1));
            sval[p] = ff[j];
            sbin[p] = (unsigned char)b;
        }
    }
    __syncthreads();

    // Copy-out: LDS-contiguous == globally contiguous within each bin region.
    const unsigned total = total_s;
    for (unsigned i = t; i < total; i += SCATTER_THREADS) {
        int b = sbin[i];
        unsigned off = (unsigned)(dstb[b] + (int)i);
        if (off < cap) {
            size_t dst = (size_t)b * cap + off;
            okeys[dst]    = skey[i];
            ocontrib[dst] = sval[i];
        }
    }
}

// One 1024-thread block per (bin, slice): accumulate into 16 KB LDS, dump partials.
__global__ __launch_bounds__(ACCUM_THREADS, 8) void accum4_kernel(
    const unsigned short* __restrict__ okeys, const float* __restrict__ ocontrib,
    const unsigned* __restrict__ gcur, unsigned cap,
    float* __restrict__ partials)
{
    __shared__ float acc[ROWS_PER_BIN];
    const int t   = threadIdx.x;
    const int bin = blockIdx.x / SLICES;
    const int sl  = blockIdx.x % SLICES;

    *reinterpret_cast<float4*>(&acc[t * 4]) = make_float4(0.f, 0.f, 0.f, 0.f);
    __syncthreads();

    unsigned count = gcur[bin];
    if (count > cap) count = cap;
    unsigned chunk = (count + SLICES - 1) / SLICES;
    chunk = (chunk + 3u) & ~3u;
    unsigned lo = (unsigned)sl * chunk;
    unsigned hi = lo + chunk; if (hi > count) hi = count;

    const unsigned short* k = okeys    + (size_t)bin * cap;
    const float*          c = ocontrib + (size_t)bin * cap;

    unsigned i = lo + (unsigned)t * 4u;
    for (; i + 3u < hi; i += (unsigned)ACCUM_THREADS * 4u) {
        ushort4 k4 = *reinterpret_cast<const ushort4*>(k + i);
        float4  c4 = *reinterpret_cast<const float4*>(c + i);
        atomicAdd(&acc[k4.x], c4.x);
        atomicAdd(&acc[k4.y], c4.y);
        atomicAdd(&acc[k4.z], c4.z);
        atomicAdd(&acc[k4.w], c4.w);
    }
    for (; i < hi; ++i) atomicAdd(&acc[k[i]], c[i]);
    __syncthreads();

    float* p = partials + (size_t)blockIdx.x * ROWS_PER_BIN;
    *reinterpret_cast<float4*>(p + t * 4) = *reinterpret_cast<const float4*>(&acc[t * 4]);
}

// Sum the SLICES partials per row (4 rows per thread, float4).
__global__ __launch_bounds__(256) void reduce4_kernel(
    const float* __restrict__ partials, float* __restrict__ y, int out_size)
{
    int r = (blockIdx.x * 256 + threadIdx.x) * 4;
    if (r >= out_size) return;
    int bin = r >> ROW_SHIFT, local = r & (ROWS_PER_BIN - 1);
    const float* p = partials + ((size_t)bin * SLICES) * ROWS_PER_BIN + local;
    float4 s = make_float4(0.f, 0.f, 0.f, 0.f);
    #pragma unroll
    for (int j = 0; j < SLICES; ++j) {
        float4 v = *reinterpret_cast<const float4*>(p + (size_t)j * ROWS_PER_BIN);
        s.x += v.x; s.y += v.y; s.z += v.z; s.w += v.w;
    }
    *reinterpret_cast<float4*>(y + r) = s;
}

extern "C" void kernel_launch(void* const* d_in, const int* in_sizes, int n_in,
                              void* d_out, int out_size, void* d_ws, size_t ws_size,
                              hipStream_t stream) {
    const float* x    = (const float*)d_in[0];
    const float* vals = (const float*)d_in[1];
    const int*   rows = (const int*)d_in[2];
    const int*   cols = (const int*)d_in[3];
    float* y = (float*)d_out;

    const int nnz = in_sizes[1];
    const int nb  = (nnz + ENT - 1) / ENT;                 // 2048
    unsigned cap  = (unsigned)(nnz / BINS) + 8192u;        // ~22 sigma slack
    cap = (cap + 3u) & ~3u;

    auto align256 = [](size_t v) { return (v + 255) & ~(size_t)255; };
    size_t off_contrib  = 0;
    size_t off_keys     = align256(off_contrib + (size_t)BINS * cap * 4);
    size_t off_partials = align256(off_keys + (size_t)BINS * cap * 2);
    size_t off_gcur     = align256(off_partials + (size_t)BINS * SLICES * ROWS_PER_BIN * 4);
    size_t need         = align256(off_gcur + (size_t)BINS * 4);

    const bool ok = (out_size <= BINS * ROWS_PER_BIN) && (out_size % 4 == 0) &&
                    (need <= ws_size) && (nnz > 0);

    if (!ok) {
        zero_out_kernel<<<(out_size + 255) / 256, 256, 0, stream>>>(y, out_size);
        spmv_coo_scatter<<<(nnz + 1023) / 1024, 256, 0, stream>>>(vals, rows, cols, x, y, nnz);
        return;
    }

    char* w = (char*)d_ws;
    float*          ocontrib = (float*)(w + off_contrib);
    unsigned short* okeys    = (unsigned short*)(w + off_keys);
    float*          partials = (float*)(w + off_partials);
    unsigned*       gcur     = (unsigned*)(w + off_gcur);

    init_cursors<<<1, BINS, 0, stream>>>(gcur);
    scatter4_kernel<<<nb, SCATTER_THREADS, 0, stream>>>(rows, cols, vals, x, nnz,
                                                        gcur, cap, okeys, ocontrib);
    accum4_kernel<<<BINS * SLICES, ACCUM_THREADS, 0, stream>>>(okeys, ocontrib, gcur, cap, partials);
    reduce4_kernel<<<(out_size / 4 + 255) / 256, 256, 0, stream>>>(partials, y, out_size);
}